// Round 5
// baseline (586.470 us; speedup 1.0000x reference)
//
#include <hip/hip_runtime.h>
#include <math.h>

#define CDIM 384
#define C3   1152
#define HH   128
#define WW   128
#define NPIX 16384
#define NHEADS 8
#define CPH  48

typedef short bf16x8 __attribute__((ext_vector_type(8)));
typedef float f32x4  __attribute__((ext_vector_type(4)));
typedef unsigned short u16x8 __attribute__((ext_vector_type(8)));
typedef _Float16 f16x8 __attribute__((ext_vector_type(8)));

__device__ __forceinline__ float bf2f(unsigned short h) {
    union { unsigned u; float f; } x; x.u = ((unsigned)h) << 16; return x.f;
}
__device__ __forceinline__ unsigned short f2bf(float f) {
    union { float f; unsigned u; } x; x.f = f;
    unsigned r = x.u + 0x7fffu + ((x.u >> 16) & 1u);
    return (unsigned short)(r >> 16);
}

#define ASYNC_CP16(gp, lp) \
    __builtin_amdgcn_global_load_lds( \
        (const __attribute__((address_space(1))) unsigned int*)(gp), \
        (__attribute__((address_space(3))) unsigned int*)(lp), 16, 0, 0)

// ---------------- fp32 -> bf16 elementwise cast (weights) ----------------
__global__ __launch_bounds__(256) void cast_bf16_kernel(
    const float* __restrict__ in, unsigned short* __restrict__ out, int n4)
{
    int i = blockIdx.x * 256 + threadIdx.x;
    if (i < n4) {
        float4 v = *(const float4*)(in + (size_t)i * 4);
        ushort4 o = { f2bf(v.x), f2bf(v.y), f2bf(v.z), f2bf(v.w) };
        *(ushort4*)(out + (size_t)i * 4) = o;
    }
}

// ---------------- transpose [K=384][NPIX] -> bf16 [NPIX][384] ----------------
template<int IN_BF16>
__global__ __launch_bounds__(256) void transpose_kernel(
    const void* __restrict__ in_, unsigned short* __restrict__ out, size_t in_zstride)
{
    const int z = blockIdx.z;
    const int n0 = blockIdx.x * 64, k0 = blockIdx.y * 64;
    __shared__ unsigned short tile[64][69];
    const int t = threadIdx.x;
    if (IN_BF16) {
        const unsigned short* in = (const unsigned short*)in_ + (size_t)z * in_zstride;
        #pragma unroll
        for (int r = 0; r < 4; ++r) {
            int kk = r * 16 + (t >> 4), nn = (t & 15) * 4;
            ushort4 v = *(const ushort4*)(in + (size_t)(k0 + kk) * NPIX + n0 + nn);
            tile[kk][nn] = v.x; tile[kk][nn + 1] = v.y;
            tile[kk][nn + 2] = v.z; tile[kk][nn + 3] = v.w;
        }
    } else {
        const float* in = (const float*)in_ + (size_t)z * in_zstride;
        #pragma unroll
        for (int r = 0; r < 4; ++r) {
            int kk = r * 16 + (t >> 4), nn = (t & 15) * 4;
            float4 v = *(const float4*)(in + (size_t)(k0 + kk) * NPIX + n0 + nn);
            tile[kk][nn] = f2bf(v.x); tile[kk][nn + 1] = f2bf(v.y);
            tile[kk][nn + 2] = f2bf(v.z); tile[kk][nn + 3] = f2bf(v.w);
        }
    }
    __syncthreads();
    unsigned short* o = out + (size_t)z * NPIX * CDIM;
    #pragma unroll
    for (int r = 0; r < 2; ++r) {
        int nn = r * 32 + (t >> 3), kk = (t & 7) * 8;
        ushort4 a, b;
        a.x = tile[kk + 0][nn]; a.y = tile[kk + 1][nn];
        a.z = tile[kk + 2][nn]; a.w = tile[kk + 3][nn];
        b.x = tile[kk + 4][nn]; b.y = tile[kk + 5][nn];
        b.z = tile[kk + 6][nn]; b.w = tile[kk + 7][nn];
        *(ushort4*)(o + (size_t)(n0 + nn) * CDIM + k0 + kk) = a;
        *(ushort4*)(o + (size_t)(n0 + nn) * CDIM + k0 + kk + 4) = b;
    }
}

// ---------------- bf16 MFMA GEMM: C[z][m][n] = sum_k A[m][k] * Bt[z][n][k] ----------------
// BK=64 (6 K-iters, half the barrier drains of BK=32). XOR-swizzled LDS: slot
// (row m, 16B-chunk c) holds global chunk c ^ (m&7); staging swizzles the GLOBAL
// address (DMA LDS dest is frozen at base+lane*16); reads apply the same XOR.
// OUT_MODE: 0 = fp32, 1 = bf16, 2 = fp16
template<int OUT_MODE, int A_PER_Z>
__global__ __launch_bounds__(256) void mfma_gemm_kernel(
    const unsigned short* __restrict__ A, const unsigned short* __restrict__ Bt,
    void* __restrict__ C, int M)
{
    const int z = blockIdx.z;
    const int n0 = blockIdx.x * 128;
    const int m0 = blockIdx.y * 128;
    const unsigned short* a = A + (A_PER_Z ? (size_t)z * M * CDIM : 0);
    const unsigned short* bt = Bt + (size_t)z * NPIX * CDIM;
    const int t = threadIdx.x;
    const int wave = t >> 6, lane = t & 63;
    const int wm = (wave & 1) * 64, wn = (wave >> 1) * 64;
    const int lm = lane & 15, lq = lane >> 4;

    __shared__ unsigned short a_s[128 * 64];   // [m][64k], 128 B rows
    __shared__ unsigned short b_s[128 * 64];

    f32x4 acc[4][4];
    #pragma unroll
    for (int i = 0; i < 4; ++i)
        #pragma unroll
        for (int j = 0; j < 4; ++j)
            acc[i][j] = (f32x4){0.f, 0.f, 0.f, 0.f};

    const int srow = t >> 3;        // 0..31 (row within 32-row pass)
    const int sc   = t & 7;         // dest chunk 0..7

    for (int k0 = 0; k0 < CDIM; k0 += 64) {
        #pragma unroll
        for (int p = 0; p < 4; ++p) {
            const int m = p * 32 + srow;
            const int src = ((sc ^ (m & 7)) * 8);
            ASYNC_CP16(a + (size_t)(m0 + m) * CDIM + k0 + src,
                       a_s + m * 64 + sc * 8);
        }
        #pragma unroll
        for (int p = 0; p < 4; ++p) {
            const int m = p * 32 + srow;
            const int src = ((sc ^ (m & 7)) * 8);
            ASYNC_CP16(bt + (size_t)(n0 + m) * CDIM + k0 + src,
                       b_s + m * 64 + sc * 8);
        }
        __syncthreads();
        #pragma unroll
        for (int s = 0; s < 2; ++s) {
            bf16x8 af[4], bfr[4];
            #pragma unroll
            for (int i = 0; i < 4; ++i) {
                const int m = wm + i * 16 + lm;
                const int pc = (s * 4 + lq) ^ (m & 7);
                af[i] = *(const bf16x8*)(a_s + m * 64 + pc * 8);
            }
            #pragma unroll
            for (int j = 0; j < 4; ++j) {
                const int m = wn + j * 16 + lm;
                const int pc = (s * 4 + lq) ^ (m & 7);
                bfr[j] = *(const bf16x8*)(b_s + m * 64 + pc * 8);
            }
            #pragma unroll
            for (int i = 0; i < 4; ++i)
                #pragma unroll
                for (int j = 0; j < 4; ++j)
                    acc[i][j] = __builtin_amdgcn_mfma_f32_16x16x32_bf16(
                        af[i], bfr[j], acc[i][j], 0, 0, 0);
        }
        __syncthreads();
    }

    if (OUT_MODE == 1) {
        unsigned short* c = (unsigned short*)C + (size_t)z * M * NPIX;
        #pragma unroll
        for (int i = 0; i < 4; ++i)
            #pragma unroll
            for (int j = 0; j < 4; ++j) {
                size_t base = (size_t)(m0 + wm + i * 16 + lq * 4) * NPIX
                            + (n0 + wn + j * 16 + lm);
                #pragma unroll
                for (int r = 0; r < 4; ++r)
                    c[base + (size_t)r * NPIX] = f2bf(acc[i][j][r]);
            }
    } else if (OUT_MODE == 2) {
        _Float16* c = (_Float16*)C + (size_t)z * M * NPIX;
        #pragma unroll
        for (int i = 0; i < 4; ++i)
            #pragma unroll
            for (int j = 0; j < 4; ++j) {
                size_t base = (size_t)(m0 + wm + i * 16 + lq * 4) * NPIX
                            + (n0 + wn + j * 16 + lm);
                #pragma unroll
                for (int r = 0; r < 4; ++r)
                    c[base + (size_t)r * NPIX] = (_Float16)acc[i][j][r];
            }
    } else {
        float* c = (float*)C + (size_t)z * M * NPIX;
        #pragma unroll
        for (int i = 0; i < 4; ++i)
            #pragma unroll
            for (int j = 0; j < 4; ++j) {
                size_t base = (size_t)(m0 + wm + i * 16 + lq * 4) * NPIX
                            + (n0 + wn + j * 16 + lm);
                #pragma unroll
                for (int r = 0; r < 4; ++r)
                    c[base + (size_t)r * NPIX] = acc[i][j][r];
            }
    }
}

// ------- helper: 10-wide bf16 window from an LDS row (vector b128 + edge scalars) -------
__device__ __forceinline__ void row10_bf(const unsigned short* row, int x0, float* a)
{
    u16x8 v = *(const u16x8*)(row + x0);
    a[0] = (x0 == 0) ? 0.f : bf2f(row[x0 - 1]);
    #pragma unroll
    for (int i = 0; i < 8; ++i) a[1 + i] = bf2f((unsigned short)v[i]);
    a[9] = (x0 == 120) ? 0.f : bf2f(row[x0 + 8]);
}

// ---------------- fast LDS-stripe depthwise 3x3 (bf16 -> bf16), fused q/k sum-of-squares ----
__global__ __launch_bounds__(256) void dwconv_fast_kernel(
    const unsigned short* __restrict__ X, const float* __restrict__ Wd,
    unsigned short* __restrict__ Y, float* __restrict__ norms2)
{
    const int z = blockIdx.z, c = blockIdx.y, s0 = blockIdx.x * 32;
    const int t = threadIdx.x;
    const unsigned short* xin = X + ((size_t)z * C3 + c) * NPIX;
    __shared__ unsigned short xs[34 * 136];

    for (int g = t; g < 34 * 16; g += 256) {
        const int r = g >> 4, cg = (g & 15) << 3;
        const int y = s0 - 1 + r;
        u16x8 v = (u16x8)(short)0;
        if (y >= 0 && y < HH) v = *(const u16x8*)(xin + y * WW + cg);
        *(u16x8*)(xs + r * 136 + cg) = v;
    }
    __syncthreads();

    float w[9];
    #pragma unroll
    for (int i = 0; i < 9; ++i) w[i] = Wd[c * 9 + i];

    const int r0 = (t >> 4) * 2, x0 = (t & 15) * 8;
    const bool do_ss = (c < 2 * CDIM);
    float ss = 0.f;
    #pragma unroll
    for (int orow = 0; orow < 2; ++orow) {
        const int ry = r0 + orow;
        float a0[10], a1[10], a2[10];
        row10_bf(xs + (ry + 0) * 136, x0, a0);
        row10_bf(xs + (ry + 1) * 136, x0, a1);
        row10_bf(xs + (ry + 2) * 136, x0, a2);
        unsigned short ob[8];
        #pragma unroll
        for (int px = 0; px < 8; ++px) {
            float s = w[0] * a0[px] + w[1] * a0[px + 1] + w[2] * a0[px + 2]
                    + w[3] * a1[px] + w[4] * a1[px + 1] + w[5] * a1[px + 2]
                    + w[6] * a2[px] + w[7] * a2[px + 1] + w[8] * a2[px + 2];
            if (do_ss) ss += s * s;
            ob[px] = f2bf(s);
        }
        *(uint4*)(Y + ((size_t)z * C3 + c) * NPIX + (s0 + ry) * WW + x0) = *(uint4*)ob;
    }

    if (do_ss) {
        #pragma unroll
        for (int off = 32; off; off >>= 1) ss += __shfl_xor(ss, off, 64);
        __shared__ float red[4];
        if ((t & 63) == 0) red[t >> 6] = ss;
        __syncthreads();
        if (t == 0) {
            const int qk = c / CDIM, ch = c % CDIM;
            atomicAdd(&norms2[((size_t)z * 2 + qk) * CDIM + ch],
                      red[0] + red[1] + red[2] + red[3]);
        }
    }
}

// ---------------- fused pos branch + final combine: out = attn(fp16) + dw(gelu(dw(v))) -----
__global__ __launch_bounds__(256) void pos_fused_kernel(
    const unsigned short* __restrict__ QKdw, const _Float16* __restrict__ Attn,
    const float* __restrict__ W1, const float* __restrict__ W2,
    float* __restrict__ Out)
{
    const int z = blockIdx.z, c = blockIdx.y, s0 = blockIdx.x * 32;
    const int t = threadIdx.x;
    const unsigned short* vin = QKdw + ((size_t)z * C3 + 2 * CDIM + c) * NPIX;
    __shared__ unsigned short vs[36 * 136];
    __shared__ float ts[34 * 132];

    for (int g = t; g < 36 * 16; g += 256) {
        const int r = g >> 4, cg = (g & 15) << 3;
        const int y = s0 - 2 + r;
        u16x8 v = (u16x8)(short)0;
        if (y >= 0 && y < HH) v = *(const u16x8*)(vin + y * WW + cg);
        *(u16x8*)(vs + r * 136 + cg) = v;
    }
    __syncthreads();

    float w1[9], w2[9];
    #pragma unroll
    for (int i = 0; i < 9; ++i) { w1[i] = W1[c * 9 + i]; w2[i] = W2[c * 9 + i]; }

    const int r0 = (t >> 4) * 2, x0 = (t & 15) * 8;

    #pragma unroll
    for (int orow = 0; orow < 2; ++orow) {
        const int tr = 1 + r0 + orow;
        float a0[10], a1[10], a2[10];
        row10_bf(vs + (tr + 0) * 136, x0, a0);
        row10_bf(vs + (tr + 1) * 136, x0, a1);
        row10_bf(vs + (tr + 2) * 136, x0, a2);
        #pragma unroll
        for (int px = 0; px < 8; ++px) {
            float s = w1[0] * a0[px] + w1[1] * a0[px + 1] + w1[2] * a0[px + 2]
                    + w1[3] * a1[px] + w1[4] * a1[px + 1] + w1[5] * a1[px + 2]
                    + w1[6] * a2[px] + w1[7] * a2[px + 1] + w1[8] * a2[px + 2];
            ts[tr * 132 + x0 + px] = 0.5f * s * (1.0f + erff(s * 0.70710678118654752f));
        }
    }
    if (t < 32) {
        const int tr = (t >> 4) ? 33 : 0;
        const int xh = (t & 15) * 8;
        const int yt = s0 - 1 + tr;
        if (yt < 0 || yt >= HH) {
            #pragma unroll
            for (int px = 0; px < 8; ++px) ts[tr * 132 + xh + px] = 0.f;
        } else {
            float a0[10], a1[10], a2[10];
            row10_bf(vs + (tr + 0) * 136, xh, a0);
            row10_bf(vs + (tr + 1) * 136, xh, a1);
            row10_bf(vs + (tr + 2) * 136, xh, a2);
            #pragma unroll
            for (int px = 0; px < 8; ++px) {
                float s = w1[0] * a0[px] + w1[1] * a0[px + 1] + w1[2] * a0[px + 2]
                        + w1[3] * a1[px] + w1[4] * a1[px + 1] + w1[5] * a1[px + 2]
                        + w1[6] * a2[px] + w1[7] * a2[px + 1] + w1[8] * a2[px + 2];
                ts[tr * 132 + xh + px] = 0.5f * s * (1.0f + erff(s * 0.70710678118654752f));
            }
        }
    }
    __syncthreads();

    float* ob = Out + ((size_t)z * CDIM + c) * NPIX;
    const _Float16* ab = Attn + ((size_t)z * CDIM + c) * NPIX;
    #pragma unroll
    for (int orow = 0; orow < 2; ++orow) {
        const int o = r0 + orow;
        float b0[10], b1[10], b2[10];
        #pragma unroll
        for (int rr = 0; rr < 3; ++rr) {
            float* dst = (rr == 0) ? b0 : (rr == 1) ? b1 : b2;
            const float* trow = ts + (o + rr) * 132;
            float4 v0 = *(const float4*)(trow + x0);
            float4 v1 = *(const float4*)(trow + x0 + 4);
            dst[0] = (x0 == 0) ? 0.f : trow[x0 - 1];
            dst[1] = v0.x; dst[2] = v0.y; dst[3] = v0.z; dst[4] = v0.w;
            dst[5] = v1.x; dst[6] = v1.y; dst[7] = v1.z; dst[8] = v1.w;
            dst[9] = (x0 == 120) ? 0.f : trow[x0 + 8];
        }
        f16x8 av = *(const f16x8*)(ab + (s0 + o) * WW + x0);
        float res[8];
        #pragma unroll
        for (int px = 0; px < 8; ++px)
            res[px] = (float)av[px]
                    + w2[0] * b0[px] + w2[1] * b0[px + 1] + w2[2] * b0[px + 2]
                    + w2[3] * b1[px] + w2[4] * b1[px + 1] + w2[5] * b1[px + 2]
                    + w2[6] * b2[px] + w2[7] * b2[px + 1] + w2[8] * b2[px + 2];
        float* op = ob + (s0 + o) * WW + x0;
        *(float4*)op = make_float4(res[0], res[1], res[2], res[3]);
        *(float4*)(op + 4) = make_float4(res[4], res[5], res[6], res[7]);
    }
}

// ---------------- scores via MFMA, fragments straight from global (K-contiguous) ----------
// 32 chunks x 8 heads x nb = up to 1024 blocks (4/CU) for latency hiding.
__global__ __launch_bounds__(256) void scores_mfma_kernel(
    const unsigned short* __restrict__ QKdw, float* __restrict__ S)
{
    const int z = blockIdx.z, h = blockIdx.y, chunk = blockIdx.x;
    const unsigned short* qb = QKdw + ((size_t)z * C3 + h * CPH) * NPIX;
    const unsigned short* kb = qb + (size_t)CDIM * NPIX;
    const int t = threadIdx.x, wave = t >> 6, lane = t & 63;
    const int lm = lane & 15, lq = lane >> 4;
    const int kw0 = chunk * 512 + wave * 128;

    f32x4 acc[3][3];
    #pragma unroll
    for (int i = 0; i < 3; ++i)
        #pragma unroll
        for (int j = 0; j < 3; ++j)
            acc[i][j] = (f32x4){0.f, 0.f, 0.f, 0.f};

    for (int ks = 0; ks < 128; ks += 32) {
        const int kk = kw0 + ks + lq * 8;
        bf16x8 af[3], bfr[3];
        #pragma unroll
        for (int i = 0; i < 3; ++i)
            af[i] = *(const bf16x8*)(qb + (size_t)(i * 16 + lm) * NPIX + kk);
        #pragma unroll
        for (int j = 0; j < 3; ++j)
            bfr[j] = *(const bf16x8*)(kb + (size_t)(j * 16 + lm) * NPIX + kk);
        #pragma unroll
        for (int i = 0; i < 3; ++i)
            #pragma unroll
            for (int j = 0; j < 3; ++j)
                acc[i][j] = __builtin_amdgcn_mfma_f32_16x16x32_bf16(
                    af[i], bfr[j], acc[i][j], 0, 0, 0);
    }
    __shared__ float s_red[CPH * CPH];
    for (int e = t; e < CPH * CPH; e += 256) s_red[e] = 0.f;
    __syncthreads();
    #pragma unroll
    for (int i = 0; i < 3; ++i)
        #pragma unroll
        for (int j = 0; j < 3; ++j)
            #pragma unroll
            for (int r = 0; r < 4; ++r)
                atomicAdd(&s_red[(i * 16 + lq * 4 + r) * CPH + j * 16 + lm], acc[i][j][r]);
    __syncthreads();
    float* Sb = S + (size_t)(z * NHEADS + h) * CPH * CPH;
    for (int e = t; e < CPH * CPH; e += 256) atomicAdd(&Sb[e], s_red[e]);
}

// ---------------- dual softmax blend (in-place on S); norms2 holds SUM OF SQUARES ---------
__global__ __launch_bounds__(64) void softmax_kernel(
    float* __restrict__ S, const float* __restrict__ norms2,
    const int* __restrict__ mask, const float* __restrict__ temp,
    const float* __restrict__ wblend)
{
    const int z = blockIdx.z, h = blockIdx.y, c = blockIdx.x;
    const int d = threadIdx.x;
    float* Srow = S + ((size_t)(z * NHEADS + h) * CPH + c) * CPH;
    const float nq = fmaxf(sqrtf(norms2[((size_t)z * 2 + 0) * CDIM + h * CPH + c]), 1e-12f);
    float a0 = -INFINITY, a1 = -INFINITY;
    if (d < CPH) {
        const float nk = fmaxf(sqrtf(norms2[((size_t)z * 2 + 1) * CDIM + h * CPH + d]), 1e-12f);
        a0 = Srow[d] / (nq * nk) * temp[h];
        a1 = (mask[(h * CPH + c) * CPH + d] == 0) ? -1e9f : a0;
    }
    float m0 = a0, m1 = a1;
    #pragma unroll
    for (int off = 32; off; off >>= 1) {
        m0 = fmaxf(m0, __shfl_xor(m0, off, 64));
        m1 = fmaxf(m1, __shfl_xor(m1, off, 64));
    }
    float e0 = (d < CPH) ? expf(a0 - m0) : 0.f;
    float e1 = (d < CPH) ? expf(a1 - m1) : 0.f;
    float s0 = e0, s1 = e1;
    #pragma unroll
    for (int off = 32; off; off >>= 1) {
        s0 += __shfl_xor(s0, off, 64);
        s1 += __shfl_xor(s1, off, 64);
    }
    const float b0 = wblend[0], b1 = wblend[1];
    const float bm = fmaxf(b0, b1);
    const float eb0 = expf(b0 - bm), eb1 = expf(b1 - bm);
    const float ws0 = eb0 / (eb0 + eb1), ws1 = eb1 / (eb0 + eb1);
    if (d < CPH) Srow[d] = (e0 / s0) * ws0 + (e1 / s1) * ws1;
}

// ---------------- Mcat[z][:, h*48+d] = P[:, h*48+c] @ A_h[c][d] ----------------
__global__ __launch_bounds__(256) void mproj_kernel(
    const float* __restrict__ S, const float* __restrict__ P,
    unsigned short* __restrict__ Mcat)
{
    const int z = blockIdx.y, h = blockIdx.x;
    __shared__ float As[CPH * CPH];
    const float* Sb = S + (size_t)(z * NHEADS + h) * CPH * CPH;
    for (int e = threadIdx.x; e < CPH * CPH; e += 256) As[e] = Sb[e];
    __syncthreads();
    unsigned short* Mz = Mcat + (size_t)z * CDIM * CDIM;
    for (int e = threadIdx.x; e < CDIM * CPH; e += 256) {
        const int m = e / CPH, d = e % CPH;
        const float* pr = P + (size_t)m * CDIM + h * CPH;
        float s = 0.f;
        #pragma unroll
        for (int c = 0; c < CPH; ++c) s = fmaf(pr[c], As[c * CPH + d], s);
        Mz[(size_t)m * CDIM + h * CPH + d] = f2bf(s);
    }
}

extern "C" void kernel_launch(void* const* d_in, const int* in_sizes, int n_in,
                              void* d_out, int out_size, void* d_ws, size_t ws_size,
                              hipStream_t stream)
{
    const float* x      = (const float*)d_in[0];
    const int*   mask   = (const int*)d_in[1];
    const float* qkv_w  = (const float*)d_in[2];
    const float* dw_w   = (const float*)d_in[3];
    const float* proj_w = (const float*)d_in[4];
    const float* temp   = (const float*)d_in[5];
    const float* wblend = (const float*)d_in[6];
    const float* pos_w1 = (const float*)d_in[7];
    const float* pos_w2 = (const float*)d_in[8];
    float* out = (float*)d_out;

    auto need = [](size_t nb) {
        return nb * ((size_t)NPIX * CDIM * 2
                   + (size_t)C3 * NPIX * 2
                   + (size_t)C3 * NPIX * 2
                   + (size_t)NHEADS * CPH * CPH * 4
                   + (size_t)2 * CDIM * 4
                   + (size_t)CDIM * CDIM * 2)
             + (size_t)C3 * CDIM * 2;
    };
    int nb = 4;
    if (need(4) > ws_size) nb = (need(2) <= ws_size) ? 2 : 1;

    char* p = (char*)d_ws;
    unsigned short* w_bf  = (unsigned short*)p; p += (size_t)C3 * CDIM * 2;
    unsigned short* x_t   = (unsigned short*)p; p += (size_t)nb * NPIX * CDIM * 2;
    unsigned short* qkv0  = (unsigned short*)p; p += (size_t)nb * C3 * NPIX * 2;
    unsigned short* qkvdw = (unsigned short*)p; p += (size_t)nb * C3 * NPIX * 2;
    float* S      = (float*)p; p += (size_t)nb * NHEADS * CPH * CPH * 4;
    float* norms2 = (float*)p; p += (size_t)nb * 2 * CDIM * 4;
    unsigned short* Mcat = (unsigned short*)p;
    unsigned short* v_t = qkv0;                   // alias: qkv0 dead by then
    _Float16* attn_h = (_Float16*)x_t;            // alias: x_t dead after qkv GEMM

    cast_bf16_kernel<<<dim3(C3 * CDIM / 4 / 256), 256, 0, stream>>>(qkv_w, w_bf, C3 * CDIM / 4);

    for (int b0 = 0; b0 < 4; b0 += nb) {
        const float* xb = x + (size_t)b0 * CDIM * NPIX;
        float* outb = out + (size_t)b0 * CDIM * NPIX;

        hipMemsetAsync(S, 0, (size_t)nb * NHEADS * CPH * CPH * 4, stream);
        hipMemsetAsync(norms2, 0, (size_t)nb * 2 * CDIM * 4, stream);

        // x -> bf16 x^T [n][k]
        transpose_kernel<0><<<dim3(NPIX / 64, CDIM / 64, nb), 256, 0, stream>>>(
            xb, x_t, (size_t)CDIM * NPIX);
        // qkv 1x1 conv: bf16 MFMA GEMM (BK=64) -> qkv0 bf16
        mfma_gemm_kernel<1, 0><<<dim3(NPIX / 128, C3 / 128, nb), 256, 0, stream>>>(
            w_bf, x_t, qkv0, C3);
        // depthwise 3x3 on all 1152 ch + fused q/k sum-of-squares
        dwconv_fast_kernel<<<dim3(4, C3, nb), 256, 0, stream>>>(
            qkv0, dw_w, qkvdw, norms2);
        // raw scores (32 chunks)
        scores_mfma_kernel<<<dim3(32, NHEADS, nb), 256, 0, stream>>>(qkvdw, S);
        // dual-softmax blend
        softmax_kernel<<<dim3(CPH, NHEADS, nb), 64, 0, stream>>>(
            S, norms2, mask, temp, wblend);
        // fold proj into attn: Mcat = [P_h @ A_h]
        mproj_kernel<<<dim3(NHEADS, nb), 256, 0, stream>>>(S, proj_w, Mcat);
        // v -> bf16 v^T [n][k]
        transpose_kernel<1><<<dim3(NPIX / 64, CDIM / 64, nb), 256, 0, stream>>>(
            qkvdw + (size_t)2 * CDIM * NPIX, v_t, (size_t)C3 * NPIX);
        // fused attn@v + proj -> fp16 scratch
        mfma_gemm_kernel<2, 1><<<dim3(NPIX / 128, CDIM / 128, nb), 256, 0, stream>>>(
            Mcat, v_t, attn_h, CDIM);
        // pos branch + final combine: out = attn + dw(gelu(dw(v)))  (pure write)
        pos_fused_kernel<<<dim3(4, CDIM, nb), 256, 0, stream>>>(
            qkvdw, attn_h, pos_w1, pos_w2, outb);
    }
}